// Round 9
// baseline (525.528 us; speedup 1.0000x reference)
//
#include <hip/hip_runtime.h>
#include <hip/hip_bf16.h>
#include <stdint.h>

// Problem constants
#define BATCH 4
#define CH 256
#define NPIX 4096
#define NGROUP 8
#define GCH 32
#define EPSV 1e-5f

typedef __attribute__((ext_vector_type(8))) short bf16x8;   // 8 bf16 = 4 VGPRs
typedef __attribute__((ext_vector_type(4))) float f32x4;
typedef __attribute__((ext_vector_type(16))) float f32x16;

#define MFMA_B16(a, b, c) __builtin_amdgcn_mfma_f32_16x16x32_bf16((a), (b), (c), 0, 0, 0)
#define MFMA32(a, b, c)   __builtin_amdgcn_mfma_f32_32x32x16_bf16((a), (b), (c), 0, 0, 0)

// global -> LDS direct copy, 16B per lane; LDS dest must be wave-uniform base + lane*16
#define GLOAD16(gsrc, ldst)                                                        \
  __builtin_amdgcn_global_load_lds(                                               \
      (const __attribute__((address_space(1))) uint32_t*)(gsrc),                  \
      (__attribute__((address_space(3))) uint32_t*)(ldst), 16, 0, 0)

__device__ __forceinline__ unsigned short f2bf(float f) {
  union { float f; uint32_t u; } v; v.f = f;
  return (unsigned short)((v.u + 0x7FFFu + ((v.u >> 16) & 1u)) >> 16);
}
__device__ __forceinline__ float bf2f(unsigned short h) {
  union { uint32_t u; float f; } v; v.u = ((uint32_t)h) << 16;
  return v.f;
}

// attention scale folded into Wq/bq, in log2 domain: 1/(16*ln2)
#define QSCALE 0.09016813306f

// ---------------------------------------------------------------------------
// Weight conversion: fp32 -> bf16; fold (scale/ln2) into Wq; stacked q|k bias
// ---------------------------------------------------------------------------
__global__ __launch_bounds__(256) void wconv(
    const float* __restrict__ Wq, const float* __restrict__ Wk,
    const float* __restrict__ Wv, const float* __restrict__ Wo,
    const float* __restrict__ bq, const float* __restrict__ bk,
    unsigned short* __restrict__ Wq_b, unsigned short* __restrict__ Wk_b,
    unsigned short* __restrict__ Wv_b, unsigned short* __restrict__ Wo_b,
    float* __restrict__ bqk_s) {
  int i = blockIdx.x * 256 + threadIdx.x;   // 65536 per weight
  Wq_b[i] = f2bf(Wq[i] * QSCALE);
  Wk_b[i] = f2bf(Wk[i]);
  Wv_b[i] = f2bf(Wv[i]);
  Wo_b[i] = f2bf(Wo[i]);
  if (i < CH) {
    bqk_s[i] = bq[i] * QSCALE;
    bqk_s[CH + i] = bk[i];
  }
}

// ---------------------------------------------------------------------------
// GroupNorm pass 1: per-(b,c) partial sums (deterministic; no atomics)
// ---------------------------------------------------------------------------
__global__ __launch_bounds__(256) void gn_stats(const float* __restrict__ x,
                                                float* __restrict__ part) {
  int bc = blockIdx.x;                       // 0 .. B*C-1
  const float* row = x + (size_t)bc * NPIX;
  int t = threadIdx.x;
  float s = 0.f, ss = 0.f;
  #pragma unroll
  for (int i = 0; i < 4; ++i) {
    f32x4 v = *(const f32x4*)(row + (i * 256 + t) * 4);
    s += v[0] + v[1] + v[2] + v[3];
    ss += v[0]*v[0] + v[1]*v[1] + v[2]*v[2] + v[3]*v[3];
  }
  #pragma unroll
  for (int m = 1; m < 64; m <<= 1) { s += __shfl_xor(s, m); ss += __shfl_xor(ss, m); }
  __shared__ float ls[8];
  if ((t & 63) == 0) { ls[(t >> 6) * 2] = s; ls[(t >> 6) * 2 + 1] = ss; }
  __syncthreads();
  if (t == 0) {
    part[bc * 2]     = ls[0] + ls[2] + ls[4] + ls[6];
    part[bc * 2 + 1] = ls[1] + ls[3] + ls[5] + ls[7];
  }
}

// ---------------------------------------------------------------------------
// GroupNorm pass 2: normalize + affine, write h transposed (B*N, C) as bf16
// ---------------------------------------------------------------------------
__global__ __launch_bounds__(256) void gn_apply(
    const float* __restrict__ x, const float* __restrict__ part,
    const float* __restrict__ gamma, const float* __restrict__ beta,
    unsigned short* __restrict__ h_t) {
  int chunk = blockIdx.x, g = blockIdx.y, b = blockIdx.z;
  int t = threadIdx.x;
  __shared__ float s_mean, s_rstd;
  __shared__ unsigned short tile[GCH][72];   // +pad
  if (t == 0) {
    float S = 0.f, SS = 0.f;
    const float* p = part + (size_t)(b * CH + g * GCH) * 2;
    for (int j = 0; j < GCH; ++j) { S += p[2 * j]; SS += p[2 * j + 1]; }
    float inv = 1.0f / (float)(GCH * NPIX);
    float mean = S * inv;
    float var = SS * inv - mean * mean;
    s_mean = mean;
    s_rstd = rsqrtf(var + EPSV);
  }
  __syncthreads();
  float mean = s_mean, rstd = s_rstd;
  int n0 = chunk * 64;
  int p = t & 63;
  int csub = t >> 6;
  #pragma unroll
  for (int cl = 0; cl < GCH; cl += 4) {
    int c = cl + csub;
    float val = x[(size_t)(b * CH + g * GCH + c) * NPIX + n0 + p];
    float gm = gamma[g * GCH + c], bt = beta[g * GCH + c];
    tile[c][p] = f2bf((val - mean) * rstd * gm + bt);
  }
  __syncthreads();
  int pix = t >> 2, cc = (t & 3) * 8;
  bf16x8 vv;
  #pragma unroll
  for (int j = 0; j < 8; ++j) vv[j] = (short)tile[cc + j][pix];
  *(bf16x8*)(h_t + (size_t)(b * NPIX + n0 + pix) * CH + g * GCH + cc) = vv;
}

// ---------------------------------------------------------------------------
// GEMM: C[M,N] = A[M,256]bf16 * Bt[N,256]bf16^T (+bias, +resid)
// 128x128 tile, BK=64, 4 waves (2x2), XOR-swizzled LDS, global_load_lds w16.
// SPLIT=1: N=512 fused q|k — cols<256 -> Cout (stride 256), else Cout2.
// ---------------------------------------------------------------------------
template <int BIAS_COL, int RESID, int OUT_BF16, int SPLIT>
__global__ __launch_bounds__(256, 2) void gemm_bt_k(
    const unsigned short* __restrict__ A, const unsigned short* __restrict__ Bt,
    void* __restrict__ Cout, const float* __restrict__ bias,
    const float* __restrict__ resid, int M, int N,
    long aStride, long btStride, long cStride, void* __restrict__ Cout2) {
  __shared__ __align__(16) unsigned short a_lds[128 * 64];
  __shared__ __align__(16) unsigned short b_lds[128 * 64];

  const int bz = blockIdx.z;
  const char* Ac = (const char*)(A + (size_t)bz * aStride);
  const char* Bc = (const char*)(Bt + (size_t)bz * btStride);
  const int m0 = blockIdx.x * 128;
  const int n0 = blockIdx.y * 128;
  const int t = threadIdx.x;
  const int w = t >> 6, l = t & 63, lr = l & 15, lk = l >> 4;
  const int wr = (w >> 1) * 64, wc = (w & 1) * 64;

  f32x4 acc[4][4];
  #pragma unroll
  for (int i = 0; i < 4; ++i)
    #pragma unroll
    for (int j = 0; j < 4; ++j) acc[i][j] = f32x4{0.f, 0.f, 0.f, 0.f};

  char* alc = (char*)a_lds;
  char* blc = (char*)b_lds;

  for (int kt = 0; kt < 4; ++kt) {
    __syncthreads();
    #pragma unroll
    for (int i = 0; i < 4; ++i) {
      int base = i * 4096 + w * 1024;
      int lin = base + l * 16;
      int sw = lin ^ (((lin >> 7) & 7) << 4);   // rows are 128B; swizzle 16B chunk
      int row = lin >> 7;
      int inr = sw & 127;
      GLOAD16(Ac + (size_t)(m0 + row) * 512 + kt * 128 + inr, alc + base);
      GLOAD16(Bc + (size_t)(n0 + row) * 512 + kt * 128 + inr, blc + base);
    }
    __syncthreads();
    #pragma unroll
    for (int ks = 0; ks < 2; ++ks) {
      bf16x8 af[4], bf[4];
      #pragma unroll
      for (int f = 0; f < 4; ++f) {
        int ra = wr + f * 16 + lr;
        int la = ra * 128 + ks * 64 + lk * 16;
        af[f] = *(const bf16x8*)(alc + (la ^ ((ra & 7) << 4)));
        int rb = wc + f * 16 + lr;
        int lb = rb * 128 + ks * 64 + lk * 16;
        bf[f] = *(const bf16x8*)(blc + (lb ^ ((rb & 7) << 4)));
      }
      #pragma unroll
      for (int mf = 0; mf < 4; ++mf)
        #pragma unroll
        for (int nf = 0; nf < 4; ++nf)
          acc[mf][nf] = MFMA_B16(af[mf], bf[nf], acc[mf][nf]);
    }
  }

  #pragma unroll
  for (int mf = 0; mf < 4; ++mf) {
    #pragma unroll
    for (int nf = 0; nf < 4; ++nf) {
      int col = n0 + wc + nf * 16 + lr;
      #pragma unroll
      for (int r = 0; r < 4; ++r) {
        int row = m0 + wr + mf * 16 + lk * 4 + r;   // C/D: col=lane&15, row=(lane>>4)*4+reg
        float val = acc[mf][nf][r];
        val += BIAS_COL ? bias[col] : bias[row];
        if (SPLIT) {
          unsigned short* dst = (col < 256) ? (unsigned short*)Cout
                                            : (unsigned short*)Cout2;
          dst[(size_t)row * 256 + (col & 255)] = f2bf(val);
        } else {
          size_t idx = (size_t)bz * (size_t)cStride + (size_t)row * N + col;
          if (RESID) val += resid[idx];
          if (OUT_BF16) ((unsigned short*)Cout)[idx] = f2bf(val);
          else          ((float*)Cout)[idx] = val;
        }
      }
    }
  }
}

// ---------------------------------------------------------------------------
// Flash attention v8: R7 structure (proven 99us) + single V buffer -> 48KB
// LDS -> 3 blocks/CU. Shifted pipeline: iter u = {PV(u-1) || QK(u)} cluster,
// softmax(u); V(u) staged END of iter u (after barrier), consumed iter u+1;
// K 2-deep. Steady-state wait vmcnt(4) = {K(u+1), V(u)}. 32x32 MFMA, swapped
// QK^T, log2 softmax, KSPLIT=4, conflict-free XOR LDS, XCD swizzle.
// ---------------------------------------------------------------------------
#define KSPLIT 4
#define KRANGE (NPIX / KSPLIT)   // 1024
#define KBLK 32
#define NT (KRANGE / KBLK)       // 32

__global__ __launch_bounds__(256, 3) void flash_kernel(
    const unsigned short* __restrict__ q_t, const unsigned short* __restrict__ k_t,
    const unsigned short* __restrict__ v,
    unsigned short* __restrict__ p0, unsigned short* __restrict__ p1,
    unsigned short* __restrict__ p2, unsigned short* __restrict__ p3,
    float* __restrict__ ml) {
  __shared__ __align__(16) unsigned short k_lds[2][KBLK * CH];   // 2 x 16KB
  __shared__ __align__(16) unsigned short v_lds[CH * KBLK];      // 16KB single

  // XCD swizzle: contiguous 64-block runs per XCD (one (b,ksp) slice pair)
  const int F = blockIdx.x;
  const int bid = (F >> 3) + ((F & 7) << 6);
  const int qx = bid & 31, b = (bid >> 5) & 3, ksp = bid >> 7;
  const int q0 = qx * 128;
  const int t = threadIdx.x;
  const int w = t >> 6, l = t & 63;
  const int l31 = l & 31, hi = l >> 5;

  // Q as B-operand fragments: lane holds Q[q=w*32+l31][d = ds*16 + hi*8 ..+8]
  bf16x8 qf[16];
  {
    const char* qp = (const char*)(q_t + (size_t)(b * NPIX + q0 + w * 32 + l31) * CH);
    #pragma unroll
    for (int ds = 0; ds < 16; ++ds)
      qf[ds] = *(const bf16x8*)(qp + ds * 32 + hi * 16);
  }

  f32x16 oacc[8];
  #pragma unroll
  for (int cf = 0; cf < 8; ++cf)
    #pragma unroll
    for (int r = 0; r < 16; ++r) oacc[cf][r] = 0.f;
  float m_run = -3e38f, l_run = 0.f;
  uint32_t pkc[8];
  #pragma unroll
  for (int m = 0; m < 8; ++m) pkc[m] = 0;

  const char* kg = (const char*)(k_t + ((size_t)b * NPIX + ksp * KRANGE) * CH);
  const char* vg = (const char*)(v + (size_t)b * CH * NPIX + ksp * KRANGE);

  // Per-lane staging offsets (loop-invariant)
  int koffb[4], voffb[4], ldsd[4];
  #pragma unroll
  for (int i_ = 0; i_ < 4; ++i_) {
    int d = i_ * 4096 + w * 1024 + l * 16;
    ldsd[i_] = d;
    int r_ = d >> 9;
    int c_ = ((d >> 4) & 31) ^ r_;
    koffb[i_] = r_ * 512 + (c_ << 4);
    voffb[i_] = ((c_ >> 2) * 32 + r_) * (NPIX * 2) + ((c_ & 3) << 4);
  }

  #define STAGE_K(buf, tt)                                                         \
    { _Pragma("unroll")                                                            \
      for (int i_ = 0; i_ < 4; ++i_)                                               \
        GLOAD16(kg + (size_t)(koffb[i_] + (tt) * (KBLK * 512)),                    \
                (char*)k_lds[buf] + ldsd[i_]); }
  #define STAGE_V(tt)                                                              \
    { _Pragma("unroll")                                                            \
      for (int i_ = 0; i_ < 4; ++i_)                                               \
        GLOAD16(vg + (size_t)(voffb[i_] + (tt) * (KBLK * 2)),                      \
                (char*)v_lds + ldsd[i_]); }

  // PV: O += P(prev) * V, A-frag built from own + cross-half pkc
  auto do_pv = [&](const char* vlcx) {
    #pragma unroll
    for (int s = 0; s < 2; ++s) {
      uint32_t own0 = hi ? pkc[4 * s + 2] : pkc[4 * s + 0];
      uint32_t own1 = hi ? pkc[4 * s + 3] : pkc[4 * s + 1];
      uint32_t snd0 = hi ? pkc[4 * s + 0] : pkc[4 * s + 2];
      uint32_t snd1 = hi ? pkc[4 * s + 1] : pkc[4 * s + 3];
      uint32_t rcv0 = (uint32_t)__shfl_xor((int)snd0, 32);
      uint32_t rcv1 = (uint32_t)__shfl_xor((int)snd1, 32);
      union { uint32_t u[4]; bf16x8 v8; } apu;
      apu.u[0] = hi ? rcv0 : own0;
      apu.u[1] = hi ? rcv1 : own1;
      apu.u[2] = hi ? own0 : rcv0;
      apu.u[3] = hi ? own1 : rcv1;
      bf16x8 ap = apu.v8;
      #pragma unroll
      for (int cf = 0; cf < 8; ++cf) {
        bf16x8 bv = *(const bf16x8*)(
            vlcx + l31 * 512 + ((((cf << 2) + (s << 1) + hi) ^ l31) << 4));
        oacc[cf] = MFMA32(ap, bv, oacc[cf]);
      }
    }
  };

  // Prologue: K(0)->kbuf0, K(1)->kbuf1; wait K(0) (oldest 4)
  STAGE_K(0, 0);
  STAGE_K(1, 1);
  asm volatile("s_waitcnt vmcnt(4)" ::: "memory");
  __builtin_amdgcn_s_barrier();

  for (int u = 0; u < NT; ++u) {
    const char* klc = (const char*)k_lds[u & 1];

    __builtin_amdgcn_s_setprio(1);
    if (u > 0) do_pv((const char*)v_lds);   // PV(u-1): independent of QK below
    f32x16 sacc;
    #pragma unroll
    for (int r = 0; r < 16; ++r) sacc[r] = 0.f;
    #pragma unroll
    for (int ds = 0; ds < 16; ++ds) {
      bf16x8 kf = *(const bf16x8*)(klc + l31 * 512 + ((((ds << 1) + hi) ^ l31) << 4));
      sacc = MFMA32(kf, qf[ds], sacc);
    }
    __builtin_amdgcn_s_setprio(0);

    // softmax(u): tree max, defer-rescale, P = 2^(S-m) packed into pkc
    float mx[8];
    #pragma unroll
    for (int r = 0; r < 8; ++r) mx[r] = fmaxf(sacc[r], sacc[r + 8]);
    #pragma unroll
    for (int st = 4; st >= 1; st >>= 1)
      #pragma unroll
      for (int r = 0; r < 4; ++r)
        if (r < st) mx[r] = fmaxf(mx[r], mx[r + st]);
    float tm = fmaxf(mx[0], __shfl_xor(mx[0], 32));

    if (!__all(tm <= m_run + 6.f)) {      // T13: P bounded by 2^6
      float mn = fmaxf(m_run, tm);
      float al = exp2f(m_run - mn);
      m_run = mn;
      l_run *= al;
      #pragma unroll
      for (int r = 0; r < 16; ++r) {
        float alr = __shfl(al, (r & 3) + 8 * (r >> 2) + 4 * hi);
        #pragma unroll
        for (int cf = 0; cf < 8; ++cf) oacc[cf][r] *= alr;
      }
    }

    float psp[4] = {0.f, 0.f, 0.f, 0.f};
    #pragma unroll
    for (int m = 0; m < 8; ++m) {
      float pa = exp2f(sacc[2 * m] - m_run);
      float pb = exp2f(sacc[2 * m + 1] - m_run);
      psp[m & 3] += pa + pb;
      union { __hip_bfloat162 h2; uint32_t u; } cv;
      cv.h2 = __float22bfloat162_rn(make_float2(pa, pb));
      pkc[m] = cv.u;
    }
    float ps = (psp[0] + psp[1]) + (psp[2] + psp[3]);
    ps += __shfl_xor(ps, 32);
    l_run += ps;

    asm volatile("" ::: "memory");
    __builtin_amdgcn_s_barrier();         // all waves done with kbuf[u&1] and v_lds
    STAGE_V(u);                           // V(u) for PV(u) in iter u+1 (or final)
    if (u + 2 < NT) STAGE_K((u & 1), u + 2);
    if (u + 2 < NT) { asm volatile("s_waitcnt vmcnt(4)" ::: "memory"); }
    else            { asm volatile("s_waitcnt vmcnt(0)" ::: "memory"); }
    __builtin_amdgcn_s_barrier();         // {K(u+1), V(u)} visible to all waves
  }

  // final PV(NT-1): V(NT-1) in v_lds
  __builtin_amdgcn_s_setprio(1);
  do_pv((const char*)v_lds);
  __builtin_amdgcn_s_setprio(0);

  // epilogue: unnormalized bf16 O-partial + (m,l) (log2-domain m)
  {
    unsigned short* opart = (ksp == 0) ? p0 : (ksp == 1) ? p1 : (ksp == 2) ? p2 : p3;
    unsigned short* op = opart + (size_t)(b * NPIX + q0 + w * 32) * CH;
    #pragma unroll
    for (int cf = 0; cf < 8; ++cf)
      #pragma unroll
      for (int r = 0; r < 16; ++r)
        op[(size_t)((r & 3) + 8 * (r >> 2) + 4 * hi) * CH + cf * 32 + l31] =
            f2bf(oacc[cf][r]);
    if (l < 32) {
      float* mlrow = ml + ((size_t)ksp * (BATCH * NPIX) +
                           b * NPIX + q0 + w * 32 + l) * 2;
      mlrow[0] = m_run;
      mlrow[1] = l_run;
    }
  }
  #undef STAGE_K
  #undef STAGE_V
}

// ---------------------------------------------------------------------------
// Merge 4 K-split partials (log2-domain m): out = sum(e_i O_i)/sum(e_i l_i)
// ---------------------------------------------------------------------------
__global__ __launch_bounds__(256) void flash_merge(
    const unsigned short* __restrict__ p0, unsigned short* __restrict__ p1io,
    const unsigned short* __restrict__ p2, const unsigned short* __restrict__ p3,
    const float* __restrict__ ml) {
  const int R = BATCH * NPIX;
  int t = threadIdx.x;
  int gr = blockIdx.x * 16 + (t >> 4);
  int colg = (t & 15) * 16;
  float m0 = ml[(size_t)gr * 2],           l0 = ml[(size_t)gr * 2 + 1];
  float m1 = ml[((size_t)R + gr) * 2],     l1 = ml[((size_t)R + gr) * 2 + 1];
  float m2 = ml[((size_t)2 * R + gr) * 2], l2 = ml[((size_t)2 * R + gr) * 2 + 1];
  float m3 = ml[((size_t)3 * R + gr) * 2], l3 = ml[((size_t)3 * R + gr) * 2 + 1];
  float m = fmaxf(fmaxf(m0, m1), fmaxf(m2, m3));
  float e0 = exp2f(m0 - m), e1 = exp2f(m1 - m);
  float e2 = exp2f(m2 - m), e3 = exp2f(m3 - m);
  float inv = 1.0f / (e0 * l0 + e1 * l1 + e2 * l2 + e3 * l3);
  const bf16x8* a0 = (const bf16x8*)(p0 + (size_t)gr * CH + colg);
  bf16x8*       a1 = (bf16x8*)(p1io + (size_t)gr * CH + colg);
  const bf16x8* a2 = (const bf16x8*)(p2 + (size_t)gr * CH + colg);
  const bf16x8* a3 = (const bf16x8*)(p3 + (size_t)gr * CH + colg);
  #pragma unroll
  for (int h = 0; h < 2; ++h) {
    bf16x8 v0 = a0[h], v1 = a1[h], v2 = a2[h], v3 = a3[h], o;
    #pragma unroll
    for (int j = 0; j < 8; ++j)
      o[j] = (short)f2bf((e0 * bf2f((unsigned short)v0[j]) +
                          e1 * bf2f((unsigned short)v1[j]) +
                          e2 * bf2f((unsigned short)v2[j]) +
                          e3 * bf2f((unsigned short)v3[j])) * inv);
    a1[h] = o;
  }
}

// ---------------------------------------------------------------------------
extern "C" void kernel_launch(void* const* d_in, const int* in_sizes, int n_in,
                              void* d_out, int out_size, void* d_ws, size_t ws_size,
                              hipStream_t stream) {
  const float* x   = (const float*)d_in[0];
  const float* gsc = (const float*)d_in[1];
  const float* gbi = (const float*)d_in[2];
  const float* Wq  = (const float*)d_in[3];
  const float* bq  = (const float*)d_in[4];
  const float* Wk  = (const float*)d_in[5];
  const float* bk  = (const float*)d_in[6];
  const float* Wv  = (const float*)d_in[7];
  const float* bv  = (const float*)d_in[8];
  const float* Wo  = (const float*)d_in[9];
  const float* bo  = (const float*)d_in[10];

  char* ws = (char*)d_ws;
  unsigned short* Wq_b = (unsigned short*)(ws);                       // 128KB
  unsigned short* Wk_b = (unsigned short*)(ws + 131072);              // adjacent: q|k stacked
  unsigned short* Wv_b = (unsigned short*)(ws + 262144);
  unsigned short* Wo_b = (unsigned short*)(ws + 393216);
  float* bqk_s         = (float*)(ws + 524288);                       // 512 floats
  float* part          = (float*)(ws + 526336);
  char* big            = ws + 534528;
  unsigned short* h_t  = (unsigned short*)(big);                      // (B*N, C); reused as O-partial 0
  unsigned short* q_t  = (unsigned short*)(big + 1 * 8388608ull);     // (B*N, C)
  unsigned short* k_t  = (unsigned short*)(big + 2 * 8388608ull);     // (B*N, C)
  unsigned short* v_   = (unsigned short*)(big + 3 * 8388608ull);     // (B, C, N)
  unsigned short* o_t  = (unsigned short*)(big + 4 * 8388608ull);     // O-partial 1 -> merged (B*N, C)
  float* ml            = (float*)(big + 5 * 8388608ull);              // [4][B*N][2] f32, 512KB
  if (ws_size < 534528 + 5ull * 8388608ull + 524288ull) return;

  // O-partials 2 and 3 live in d_out (16MB fp32 buffer = exactly 2x 8MB bf16)
  unsigned short* dout_u = (unsigned short*)d_out;
  unsigned short* op2 = dout_u;
  unsigned short* op3 = dout_u + 4194304;

  wconv<<<256, 256, 0, stream>>>(Wq, Wk, Wv, Wo, bq, bk,
                                 Wq_b, Wk_b, Wv_b, Wo_b, bqk_s);
  gn_stats<<<BATCH * CH, 256, 0, stream>>>(x, part);
  gn_apply<<<dim3(64, NGROUP, BATCH), 256, 0, stream>>>(x, part, gsc, gbi, h_t);

  // fused q|k: [q_t | k_t] = h_t @ [Wq*QSCALE | Wk]^T + [bq*QSCALE | bk]
  gemm_bt_k<1, 0, 1, 1><<<dim3(128, 4, 1), 256, 0, stream>>>(
      h_t, Wq_b, q_t, bqk_s, nullptr, 16384, 512, 0, 0, 0, k_t);
  // v = Wv @ h + bv, stored (C, N) per batch  (M=256, N=4096)
  gemm_bt_k<0, 0, 1, 0><<<dim3(2, 32, BATCH), 256, 0, stream>>>(
      Wv_b, h_t, v_, bv, nullptr, 256, 4096, 0, 1048576, 1048576, nullptr);

  // flash: h_t dead -> partial0; o_t -> partial1; d_out halves -> partial2/3
  flash_kernel<<<dim3(32 * BATCH * KSPLIT, 1, 1), 256, 0, stream>>>(
      q_t, k_t, v_, h_t, o_t, op2, op3, ml);
  flash_merge<<<(BATCH * NPIX) / 16, 256, 0, stream>>>(h_t, o_t, op2, op3, ml);

  // out = Wo @ attn_out + bo + input  (fp32, (B, C, N)) — overwrites partial scratch
  gemm_bt_k<0, 1, 0, 0><<<dim3(2, 32, BATCH), 256, 0, stream>>>(
      Wo_b, o_t, (float*)d_out, bo, x, 256, 4096, 0, 1048576, 1048576, nullptr);
}

// Round 10
// 141.109 us; speedup vs baseline: 3.7243x; 3.7243x over previous
//
#include <hip/hip_runtime.h>
#include <hip/hip_bf16.h>
#include <stdint.h>

// Problem constants
#define BATCH 4
#define CH 256
#define NPIX 4096
#define NGROUP 8
#define GCH 32
#define EPSV 1e-5f

typedef __attribute__((ext_vector_type(8))) short bf16x8;   // 8 bf16 = 4 VGPRs
typedef __attribute__((ext_vector_type(4))) float f32x4;
typedef __attribute__((ext_vector_type(16))) float f32x16;

#define MFMA_B16(a, b, c) __builtin_amdgcn_mfma_f32_16x16x32_bf16((a), (b), (c), 0, 0, 0)
#define MFMA32(a, b, c)   __builtin_amdgcn_mfma_f32_32x32x16_bf16((a), (b), (c), 0, 0, 0)

// global -> LDS direct copy, 16B per lane; LDS dest must be wave-uniform base + lane*16
#define GLOAD16(gsrc, ldst)                                                        \
  __builtin_amdgcn_global_load_lds(                                               \
      (const __attribute__((address_space(1))) uint32_t*)(gsrc),                  \
      (__attribute__((address_space(3))) uint32_t*)(ldst), 16, 0, 0)

__device__ __forceinline__ unsigned short f2bf(float f) {
  union { float f; uint32_t u; } v; v.f = f;
  return (unsigned short)((v.u + 0x7FFFu + ((v.u >> 16) & 1u)) >> 16);
}
__device__ __forceinline__ float bf2f(unsigned short h) {
  union { uint32_t u; float f; } v; v.u = ((uint32_t)h) << 16;
  return v.f;
}

// attention scale folded into Wq/bq, in log2 domain: 1/(16*ln2)
#define QSCALE 0.09016813306f

// ---------------------------------------------------------------------------
// Weight conversion: fp32 -> bf16; fold (scale/ln2) into Wq; stacked q|k bias
// ---------------------------------------------------------------------------
__global__ __launch_bounds__(256) void wconv(
    const float* __restrict__ Wq, const float* __restrict__ Wk,
    const float* __restrict__ Wv, const float* __restrict__ Wo,
    const float* __restrict__ bq, const float* __restrict__ bk,
    unsigned short* __restrict__ Wq_b, unsigned short* __restrict__ Wk_b,
    unsigned short* __restrict__ Wv_b, unsigned short* __restrict__ Wo_b,
    float* __restrict__ bqk_s) {
  int i = blockIdx.x * 256 + threadIdx.x;   // 65536 per weight
  Wq_b[i] = f2bf(Wq[i] * QSCALE);
  Wk_b[i] = f2bf(Wk[i]);
  Wv_b[i] = f2bf(Wv[i]);
  Wo_b[i] = f2bf(Wo[i]);
  if (i < CH) {
    bqk_s[i] = bq[i] * QSCALE;
    bqk_s[CH + i] = bk[i];
  }
}

// ---------------------------------------------------------------------------
// GroupNorm pass 1: per-(b,c) partial sums (deterministic; no atomics)
// ---------------------------------------------------------------------------
__global__ __launch_bounds__(256) void gn_stats(const float* __restrict__ x,
                                                float* __restrict__ part) {
  int bc = blockIdx.x;                       // 0 .. B*C-1
  const float* row = x + (size_t)bc * NPIX;
  int t = threadIdx.x;
  float s = 0.f, ss = 0.f;
  #pragma unroll
  for (int i = 0; i < 4; ++i) {
    f32x4 v = *(const f32x4*)(row + (i * 256 + t) * 4);
    s += v[0] + v[1] + v[2] + v[3];
    ss += v[0]*v[0] + v[1]*v[1] + v[2]*v[2] + v[3]*v[3];
  }
  #pragma unroll
  for (int m = 1; m < 64; m <<= 1) { s += __shfl_xor(s, m); ss += __shfl_xor(ss, m); }
  __shared__ float ls[8];
  if ((t & 63) == 0) { ls[(t >> 6) * 2] = s; ls[(t >> 6) * 2 + 1] = ss; }
  __syncthreads();
  if (t == 0) {
    part[bc * 2]     = ls[0] + ls[2] + ls[4] + ls[6];
    part[bc * 2 + 1] = ls[1] + ls[3] + ls[5] + ls[7];
  }
}

// ---------------------------------------------------------------------------
// GroupNorm pass 2: normalize + affine, write h transposed (B*N, C) as bf16
// ---------------------------------------------------------------------------
__global__ __launch_bounds__(256) void gn_apply(
    const float* __restrict__ x, const float* __restrict__ part,
    const float* __restrict__ gamma, const float* __restrict__ beta,
    unsigned short* __restrict__ h_t) {
  int chunk = blockIdx.x, g = blockIdx.y, b = blockIdx.z;
  int t = threadIdx.x;
  __shared__ float s_mean, s_rstd;
  __shared__ unsigned short tile[GCH][72];   // +pad
  if (t == 0) {
    float S = 0.f, SS = 0.f;
    const float* p = part + (size_t)(b * CH + g * GCH) * 2;
    for (int j = 0; j < GCH; ++j) { S += p[2 * j]; SS += p[2 * j + 1]; }
    float inv = 1.0f / (float)(GCH * NPIX);
    float mean = S * inv;
    float var = SS * inv - mean * mean;
    s_mean = mean;
    s_rstd = rsqrtf(var + EPSV);
  }
  __syncthreads();
  float mean = s_mean, rstd = s_rstd;
  int n0 = chunk * 64;
  int p = t & 63;
  int csub = t >> 6;
  #pragma unroll
  for (int cl = 0; cl < GCH; cl += 4) {
    int c = cl + csub;
    float val = x[(size_t)(b * CH + g * GCH + c) * NPIX + n0 + p];
    float gm = gamma[g * GCH + c], bt = beta[g * GCH + c];
    tile[c][p] = f2bf((val - mean) * rstd * gm + bt);
  }
  __syncthreads();
  int pix = t >> 2, cc = (t & 3) * 8;
  bf16x8 vv;
  #pragma unroll
  for (int j = 0; j < 8; ++j) vv[j] = (short)tile[cc + j][pix];
  *(bf16x8*)(h_t + (size_t)(b * NPIX + n0 + pix) * CH + g * GCH + cc) = vv;
}

// ---------------------------------------------------------------------------
// GEMM: C[M,N] = A[M,256]bf16 * Bt[N,256]bf16^T (+bias, +resid)
// 128x128 tile, BK=64, 4 waves (2x2), XOR-swizzled LDS, global_load_lds w16.
// SPLIT=1: N=512 fused q|k — cols<256 -> Cout (stride 256), else Cout2.
// ---------------------------------------------------------------------------
template <int BIAS_COL, int RESID, int OUT_BF16, int SPLIT>
__global__ __launch_bounds__(256, 2) void gemm_bt_k(
    const unsigned short* __restrict__ A, const unsigned short* __restrict__ Bt,
    void* __restrict__ Cout, const float* __restrict__ bias,
    const float* __restrict__ resid, int M, int N,
    long aStride, long btStride, long cStride, void* __restrict__ Cout2) {
  __shared__ __align__(16) unsigned short a_lds[128 * 64];
  __shared__ __align__(16) unsigned short b_lds[128 * 64];

  const int bz = blockIdx.z;
  const char* Ac = (const char*)(A + (size_t)bz * aStride);
  const char* Bc = (const char*)(Bt + (size_t)bz * btStride);
  const int m0 = blockIdx.x * 128;
  const int n0 = blockIdx.y * 128;
  const int t = threadIdx.x;
  const int w = t >> 6, l = t & 63, lr = l & 15, lk = l >> 4;
  const int wr = (w >> 1) * 64, wc = (w & 1) * 64;

  f32x4 acc[4][4];
  #pragma unroll
  for (int i = 0; i < 4; ++i)
    #pragma unroll
    for (int j = 0; j < 4; ++j) acc[i][j] = f32x4{0.f, 0.f, 0.f, 0.f};

  char* alc = (char*)a_lds;
  char* blc = (char*)b_lds;

  for (int kt = 0; kt < 4; ++kt) {
    __syncthreads();
    #pragma unroll
    for (int i = 0; i < 4; ++i) {
      int base = i * 4096 + w * 1024;
      int lin = base + l * 16;
      int sw = lin ^ (((lin >> 7) & 7) << 4);   // rows are 128B; swizzle 16B chunk
      int row = lin >> 7;
      int inr = sw & 127;
      GLOAD16(Ac + (size_t)(m0 + row) * 512 + kt * 128 + inr, alc + base);
      GLOAD16(Bc + (size_t)(n0 + row) * 512 + kt * 128 + inr, blc + base);
    }
    __syncthreads();
    #pragma unroll
    for (int ks = 0; ks < 2; ++ks) {
      bf16x8 af[4], bf[4];
      #pragma unroll
      for (int f = 0; f < 4; ++f) {
        int ra = wr + f * 16 + lr;
        int la = ra * 128 + ks * 64 + lk * 16;
        af[f] = *(const bf16x8*)(alc + (la ^ ((ra & 7) << 4)));
        int rb = wc + f * 16 + lr;
        int lb = rb * 128 + ks * 64 + lk * 16;
        bf[f] = *(const bf16x8*)(blc + (lb ^ ((rb & 7) << 4)));
      }
      #pragma unroll
      for (int mf = 0; mf < 4; ++mf)
        #pragma unroll
        for (int nf = 0; nf < 4; ++nf)
          acc[mf][nf] = MFMA_B16(af[mf], bf[nf], acc[mf][nf]);
    }
  }

  #pragma unroll
  for (int mf = 0; mf < 4; ++mf) {
    #pragma unroll
    for (int nf = 0; nf < 4; ++nf) {
      int col = n0 + wc + nf * 16 + lr;
      #pragma unroll
      for (int r = 0; r < 4; ++r) {
        int row = m0 + wr + mf * 16 + lk * 4 + r;   // C/D: col=lane&15, row=(lane>>4)*4+reg
        float val = acc[mf][nf][r];
        val += BIAS_COL ? bias[col] : bias[row];
        if (SPLIT) {
          unsigned short* dst = (col < 256) ? (unsigned short*)Cout
                                            : (unsigned short*)Cout2;
          dst[(size_t)row * 256 + (col & 255)] = f2bf(val);
        } else {
          size_t idx = (size_t)bz * (size_t)cStride + (size_t)row * N + col;
          if (RESID) val += resid[idx];
          if (OUT_BF16) ((unsigned short*)Cout)[idx] = f2bf(val);
          else          ((float*)Cout)[idx] = val;
        }
      }
    }
  }
}

// ---------------------------------------------------------------------------
// Flash attention v6 (proven 99us @ R7): shifted pipeline — iteration u runs
// ONE merged 32-MFMA cluster {PV(u-1) || QK^T(u)} then softmax(u); P carried
// in registers. K(u) in kbuf[u&1]; V(u) in vbuf[u&1], consumed at iter u+1.
// End of iter u stages K(u+2)->kbuf[u&1], V(u+1)->vbuf[(u+1)&1]; vmcnt(8) =
// {K(u+1),V(u)}. 32x32 MFMA, swapped QK^T, log2-domain lane-local softmax,
// KSPLIT=4, conflict-free 5-bit XOR LDS, XCD-aware swizzle.
// ---------------------------------------------------------------------------
#define KSPLIT 4
#define KRANGE (NPIX / KSPLIT)   // 1024
#define KBLK 32
#define NT (KRANGE / KBLK)       // 32

__global__ __launch_bounds__(256, 2) void flash_kernel(
    const unsigned short* __restrict__ q_t, const unsigned short* __restrict__ k_t,
    const unsigned short* __restrict__ v,
    unsigned short* __restrict__ p0, unsigned short* __restrict__ p1,
    unsigned short* __restrict__ p2, unsigned short* __restrict__ p3,
    float* __restrict__ ml) {
  __shared__ __align__(16) unsigned short k_lds[2][KBLK * CH];   // 2 x 16KB
  __shared__ __align__(16) unsigned short v_lds[2][CH * KBLK];   // 2 x 16KB

  // XCD swizzle: contiguous 64-block runs per XCD (one (b,ksp) slice pair)
  const int F = blockIdx.x;
  const int bid = (F >> 3) + ((F & 7) << 6);
  const int qx = bid & 31, b = (bid >> 5) & 3, ksp = bid >> 7;
  const int q0 = qx * 128;
  const int t = threadIdx.x;
  const int w = t >> 6, l = t & 63;
  const int l31 = l & 31, hi = l >> 5;

  // Q as B-operand fragments: lane holds Q[q=w*32+l31][d = ds*16 + hi*8 ..+8]
  bf16x8 qf[16];
  {
    const char* qp = (const char*)(q_t + (size_t)(b * NPIX + q0 + w * 32 + l31) * CH);
    #pragma unroll
    for (int ds = 0; ds < 16; ++ds)
      qf[ds] = *(const bf16x8*)(qp + ds * 32 + hi * 16);
  }

  f32x16 oacc[8];
  #pragma unroll
  for (int cf = 0; cf < 8; ++cf)
    #pragma unroll
    for (int r = 0; r < 16; ++r) oacc[cf][r] = 0.f;
  float m_run = -3e38f, l_run = 0.f;
  uint32_t pkc[8];
  #pragma unroll
  for (int m = 0; m < 8; ++m) pkc[m] = 0;

  const char* kg = (const char*)(k_t + ((size_t)b * NPIX + ksp * KRANGE) * CH);
  const char* vg = (const char*)(v + (size_t)b * CH * NPIX + ksp * KRANGE);

  // Precompute per-lane staging offsets (loop-invariant; +tt*stride per tile)
  int koffb[4], voffb[4], ldsd[4];
  #pragma unroll
  for (int i_ = 0; i_ < 4; ++i_) {
    int d = i_ * 4096 + w * 1024 + l * 16;
    ldsd[i_] = d;
    int r_ = d >> 9;
    int c_ = ((d >> 4) & 31) ^ r_;
    koffb[i_] = r_ * 512 + (c_ << 4);
    voffb[i_] = ((c_ >> 2) * 32 + r_) * (NPIX * 2) + ((c_ & 3) << 4);
  }

  #define STAGE_K(buf, tt)                                                         \
    { _Pragma("unroll")                                                            \
      for (int i_ = 0; i_ < 4; ++i_)                                               \
        GLOAD16(kg + (size_t)(koffb[i_] + (tt) * (KBLK * 512)),                    \
                (char*)k_lds[buf] + ldsd[i_]); }
  #define STAGE_V(buf, tt)                                                         \
    { _Pragma("unroll")                                                            \
      for (int i_ = 0; i_ < 4; ++i_)                                               \
        GLOAD16(vg + (size_t)(voffb[i_] + (tt) * (KBLK * 2)),                      \
                (char*)v_lds[buf] + ldsd[i_]); }

  // PV: O += P(prev) * V, A-frag built from own + cross-half pkc
  auto do_pv = [&](const char* vlcx) {
    #pragma unroll
    for (int s = 0; s < 2; ++s) {
      uint32_t own0 = hi ? pkc[4 * s + 2] : pkc[4 * s + 0];
      uint32_t own1 = hi ? pkc[4 * s + 3] : pkc[4 * s + 1];
      uint32_t snd0 = hi ? pkc[4 * s + 0] : pkc[4 * s + 2];
      uint32_t snd1 = hi ? pkc[4 * s + 1] : pkc[4 * s + 3];
      uint32_t rcv0 = (uint32_t)__shfl_xor((int)snd0, 32);
      uint32_t rcv1 = (uint32_t)__shfl_xor((int)snd1, 32);
      union { uint32_t u[4]; bf16x8 v8; } apu;
      apu.u[0] = hi ? rcv0 : own0;
      apu.u[1] = hi ? rcv1 : own1;
      apu.u[2] = hi ? own0 : rcv0;
      apu.u[3] = hi ? own1 : rcv1;
      bf16x8 ap = apu.v8;
      #pragma unroll
      for (int cf = 0; cf < 8; ++cf) {
        bf16x8 bv = *(const bf16x8*)(
            vlcx + l31 * 512 + ((((cf << 2) + (s << 1) + hi) ^ l31) << 4));
        oacc[cf] = MFMA32(ap, bv, oacc[cf]);
      }
    }
  };

  // Prologue: K(0)->kbuf0, K(1)->kbuf1, V(0)->vbuf0; wait K(0) (oldest 4)
  STAGE_K(0, 0);
  STAGE_K(1, 1);
  STAGE_V(0, 0);
  asm volatile("s_waitcnt vmcnt(8)" ::: "memory");
  __builtin_amdgcn_s_barrier();

  for (int u = 0; u < NT; ++u) {
    const char* klc = (const char*)k_lds[u & 1];
    const char* vlc = (const char*)v_lds[(u ^ 1) & 1];   // V(u-1)

    __builtin_amdgcn_s_setprio(1);
    if (u > 0) do_pv(vlc);                // PV(u-1): independent of QK below
    f32x16 sacc;
    #pragma unroll
    for (int r = 0; r < 16; ++r) sacc[r] = 0.f;
    #pragma unroll
    for (int ds = 0; ds < 16; ++ds) {
      bf16x8 kf = *(const bf16x8*)(klc + l31 * 512 + ((((ds << 1) + hi) ^ l31) << 4));
      sacc = MFMA32(kf, qf[ds], sacc);
    }
    __builtin_amdgcn_s_setprio(0);

    // softmax(u): tree max, defer-rescale, P = 2^(S-m) packed into pkc
    float mx[8];
    #pragma unroll
    for (int r = 0; r < 8; ++r) mx[r] = fmaxf(sacc[r], sacc[r + 8]);
    #pragma unroll
    for (int st = 4; st >= 1; st >>= 1)
      #pragma unroll
      for (int r = 0; r < 4; ++r)
        if (r < st) mx[r] = fmaxf(mx[r], mx[r + st]);
    float tm = fmaxf(mx[0], __shfl_xor(mx[0], 32));

    if (!__all(tm <= m_run + 6.f)) {      // T13: P bounded by 2^6
      float mn = fmaxf(m_run, tm);
      float al = exp2f(m_run - mn);
      m_run = mn;
      l_run *= al;
      #pragma unroll
      for (int r = 0; r < 16; ++r) {
        float alr = __shfl(al, (r & 3) + 8 * (r >> 2) + 4 * hi);
        #pragma unroll
        for (int cf = 0; cf < 8; ++cf) oacc[cf][r] *= alr;
      }
    }

    float psp[4] = {0.f, 0.f, 0.f, 0.f};
    #pragma unroll
    for (int m = 0; m < 8; ++m) {
      float pa = exp2f(sacc[2 * m] - m_run);
      float pb = exp2f(sacc[2 * m + 1] - m_run);
      psp[m & 3] += pa + pb;
      union { __hip_bfloat162 h2; uint32_t u; } cv;
      cv.h2 = __float22bfloat162_rn(make_float2(pa, pb));
      pkc[m] = cv.u;
    }
    float ps = (psp[0] + psp[1]) + (psp[2] + psp[3]);
    ps += __shfl_xor(ps, 32);
    l_run += ps;

    asm volatile("" ::: "memory");
    __builtin_amdgcn_s_barrier();         // all waves done with kbuf[u&1], vbuf[(u-1)&1]
    if (u + 2 < NT) STAGE_K((u & 1), u + 2);
    if (u + 1 < NT) STAGE_V(((u + 1) & 1), u + 1);
    if (u + 2 < NT)      { asm volatile("s_waitcnt vmcnt(8)" ::: "memory"); }
    else if (u + 1 < NT) { asm volatile("s_waitcnt vmcnt(4)" ::: "memory"); }
    else                 { asm volatile("s_waitcnt vmcnt(0)" ::: "memory"); }
    __builtin_amdgcn_s_barrier();         // {K(u+1), V(u)} visible to all waves
  }

  // final PV(NT-1): V(NT-1) sits in vbuf[(NT-1)&1]
  __builtin_amdgcn_s_setprio(1);
  do_pv((const char*)v_lds[(NT - 1) & 1]);
  __builtin_amdgcn_s_setprio(0);

  // epilogue: unnormalized bf16 O-partial + (m,l) (log2-domain m)
  {
    unsigned short* opart = (ksp == 0) ? p0 : (ksp == 1) ? p1 : (ksp == 2) ? p2 : p3;
    unsigned short* op = opart + (size_t)(b * NPIX + q0 + w * 32) * CH;
    #pragma unroll
    for (int cf = 0; cf < 8; ++cf)
      #pragma unroll
      for (int r = 0; r < 16; ++r)
        op[(size_t)((r & 3) + 8 * (r >> 2) + 4 * hi) * CH + cf * 32 + l31] =
            f2bf(oacc[cf][r]);
    if (l < 32) {
      float* mlrow = ml + ((size_t)ksp * (BATCH * NPIX) +
                           b * NPIX + q0 + w * 32 + l) * 2;
      mlrow[0] = m_run;
      mlrow[1] = l_run;
    }
  }
  #undef STAGE_K
  #undef STAGE_V
}

// ---------------------------------------------------------------------------
// Merge 4 K-split partials (log2-domain m): out = sum(e_i O_i)/sum(e_i l_i)
// ---------------------------------------------------------------------------
__global__ __launch_bounds__(256) void flash_merge(
    const unsigned short* __restrict__ p0, unsigned short* __restrict__ p1io,
    const unsigned short* __restrict__ p2, const unsigned short* __restrict__ p3,
    const float* __restrict__ ml) {
  const int R = BATCH * NPIX;
  int t = threadIdx.x;
  int gr = blockIdx.x * 16 + (t >> 4);
  int colg = (t & 15) * 16;
  float m0 = ml[(size_t)gr * 2],           l0 = ml[(size_t)gr * 2 + 1];
  float m1 = ml[((size_t)R + gr) * 2],     l1 = ml[((size_t)R + gr) * 2 + 1];
  float m2 = ml[((size_t)2 * R + gr) * 2], l2 = ml[((size_t)2 * R + gr) * 2 + 1];
  float m3 = ml[((size_t)3 * R + gr) * 2], l3 = ml[((size_t)3 * R + gr) * 2 + 1];
  float m = fmaxf(fmaxf(m0, m1), fmaxf(m2, m3));
  float e0 = exp2f(m0 - m), e1 = exp2f(m1 - m);
  float e2 = exp2f(m2 - m), e3 = exp2f(m3 - m);
  float inv = 1.0f / (e0 * l0 + e1 * l1 + e2 * l2 + e3 * l3);
  const bf16x8* a0 = (const bf16x8*)(p0 + (size_t)gr * CH + colg);
  bf16x8*       a1 = (bf16x8*)(p1io + (size_t)gr * CH + colg);
  const bf16x8* a2 = (const bf16x8*)(p2 + (size_t)gr * CH + colg);
  const bf16x8* a3 = (const bf16x8*)(p3 + (size_t)gr * CH + colg);
  #pragma unroll
  for (int h = 0; h < 2; ++h) {
    bf16x8 v0 = a0[h], v1 = a1[h], v2 = a2[h], v3 = a3[h], o;
    #pragma unroll
    for (int j = 0; j < 8; ++j)
      o[j] = (short)f2bf((e0 * bf2f((unsigned short)v0[j]) +
                          e1 * bf2f((unsigned short)v1[j]) +
                          e2 * bf2f((unsigned short)v2[j]) +
                          e3 * bf2f((unsigned short)v3[j])) * inv);
    a1[h] = o;
  }
}

// ---------------------------------------------------------------------------
extern "C" void kernel_launch(void* const* d_in, const int* in_sizes, int n_in,
                              void* d_out, int out_size, void* d_ws, size_t ws_size,
                              hipStream_t stream) {
  const float* x   = (const float*)d_in[0];
  const float* gsc = (const float*)d_in[1];
  const float* gbi = (const float*)d_in[2];
  const float* Wq  = (const float*)d_in[3];
  const float* bq  = (const float*)d_in[4];
  const float* Wk  = (const float*)d_in[5];
  const float* bk  = (const float*)d_in[6];
  const float* Wv  = (const float*)d_in[7];
  const float* bv  = (const float*)d_in[8];
  const float* Wo  = (const float*)d_in[9];
  const float* bo  = (const float*)d_in[10];

  char* ws = (char*)d_ws;
  unsigned short* Wq_b = (unsigned short*)(ws);                       // 128KB
  unsigned short* Wk_b = (unsigned short*)(ws + 131072);              // adjacent: q|k stacked
  unsigned short* Wv_b = (unsigned short*)(ws + 262144);
  unsigned short* Wo_b = (unsigned short*)(ws + 393216);
  float* bqk_s         = (float*)(ws + 524288);                       // 512 floats
  float* part          = (float*)(ws + 526336);
  char* big            = ws + 534528;
  unsigned short* h_t  = (unsigned short*)(big);                      // (B*N, C); reused as O-partial 0
  unsigned short* q_t  = (unsigned short*)(big + 1 * 8388608ull);     // (B*N, C)
  unsigned short* k_t  = (unsigned short*)(big + 2 * 8388608ull);     // (B*N, C)
  unsigned short* v_   = (unsigned short*)(big + 3 * 8388608ull);     // (B, C, N)
  unsigned short* o_t  = (unsigned short*)(big + 4 * 8388608ull);     // O-partial 1 -> merged (B*N, C)
  float* ml            = (float*)(big + 5 * 8388608ull);              // [4][B*N][2] f32, 512KB
  if (ws_size < 534528 + 5ull * 8388608ull + 524288ull) return;

  // O-partials 2 and 3 live in d_out (16MB fp32 buffer = exactly 2x 8MB bf16)
  unsigned short* dout_u = (unsigned short*)d_out;
  unsigned short* op2 = dout_u;
  unsigned short* op3 = dout_u + 4194304;

  wconv<<<256, 256, 0, stream>>>(Wq, Wk, Wv, Wo, bq, bk,
                                 Wq_b, Wk_b, Wv_b, Wo_b, bqk_s);
  gn_stats<<<BATCH * CH, 256, 0, stream>>>(x, part);
  gn_apply<<<dim3(64, NGROUP, BATCH), 256, 0, stream>>>(x, part, gsc, gbi, h_t);

  // fused q|k: [q_t | k_t] = h_t @ [Wq*QSCALE | Wk]^T + [bq*QSCALE | bk]
  gemm_bt_k<1, 0, 1, 1><<<dim3(128, 4, 1), 256, 0, stream>>>(
      h_t, Wq_b, q_t, bqk_s, nullptr, 16384, 512, 0, 0, 0, k_t);
  // v = Wv @ h + bv, stored (C, N) per batch  (M=256, N=4096)
  gemm_bt_k<0, 0, 1, 0><<<dim3(2, 32, BATCH), 256, 0, stream>>>(
      Wv_b, h_t, v_, bv, nullptr, 256, 4096, 0, 1048576, 1048576, nullptr);

  // flash: h_t dead -> partial0; o_t -> partial1; d_out halves -> partial2/3
  flash_kernel<<<dim3(32 * BATCH * KSPLIT, 1, 1), 256, 0, stream>>>(
      q_t, k_t, v_, h_t, o_t, op2, op3, ml);
  flash_merge<<<(BATCH * NPIX) / 16, 256, 0, stream>>>(h_t, o_t, op2, op3, ml);

  // out = Wo @ attn_out + bo + input  (fp32, (B, C, N)) — overwrites partial scratch
  gemm_bt_k<0, 1, 0, 0><<<dim3(2, 32, BATCH), 256, 0, stream>>>(
      Wo_b, o_t, (float*)d_out, bo, x, 256, 4096, 0, 1048576, 1048576, nullptr);
}